// Round 1
// baseline (207.561 us; speedup 1.0000x reference)
//
#include <hip/hip_runtime.h>

#define THREADS 256
#define HW 16384        // H*W per (b,c) row
#define K_SEL 8192      // k = 0.5 * H * W
#define NB1 2048        // pass-1 bins: abs bits [30:20]
#define NB2 1024        // pass-2/3 bins: 10 bits each

// Find the kRem-th largest bin position in hist[nbins] (bins ascending in value).
// Executed by wave 0 only (threads 0..63). Writes selected bin and residual rank.
__device__ __forceinline__ void wave_find(const unsigned* hist, int nbins, unsigned kRem,
                                          unsigned* bc_bin, unsigned* bc_k) {
  const int lane = (int)threadIdx.x;          // 0..63
  const int bpl = nbins >> 6;                 // bins per lane (contiguous chunk)
  const int base = lane * bpl;
  // Bank-rotated chunk sum: lane l reads its bins in rotated order -> conflict-free.
  unsigned s = 0;
  for (int j = 0; j < bpl; ++j) s += hist[base + ((j + lane) & (bpl - 1))];
  // Inclusive suffix sum across lanes: suf_l = sum_{u>=l} s_u  (higher lanes = larger values)
  unsigned suf = s;
#pragma unroll
  for (int off = 1; off < 64; off <<= 1) {
    unsigned v = __shfl_down(suf, off);
    if (lane + off < 64) suf += v;
  }
  // Unique lane where cumAbove < kRem <= cumAbove + s  (cumAbove = suf - s)
  const bool hit = ((suf - s) < kRem) && (kRem <= suf);
  const unsigned long long m = __ballot(hit);
  const int tl = (int)__builtin_ctzll(m);
  if (lane == tl) {
    unsigned cum = suf - s;
    int bin = base + bpl - 1;
    for (;; --bin) {
      const unsigned h = hist[bin];
      if (cum + h >= kRem) { bc_bin[0] = (unsigned)bin; bc_k[0] = kRem - cum; break; }
      cum += h;
    }
  }
}

extern "C" __global__ __launch_bounds__(THREADS, 2)
void sparsify_topk_kernel(const float* __restrict__ x, float* __restrict__ out) {
  extern __shared__ __align__(16) unsigned smem[];
  unsigned* data = smem;               // HW words (raw float bits)
  unsigned* hist = smem + HW;          // NB1 words
  unsigned* bc   = smem + HW + NB1;    // 2 words broadcast {bin, kRem}
  uint4* data4 = (uint4*)smem;

  const int t = (int)threadIdx.x;
  const size_t rowOff = (size_t)blockIdx.x * (HW / 4);
  const uint4* src = (const uint4*)x + rowOff;
  uint4*       dst = (uint4*)out + rowOff;

  // zero pass-1 histogram
  for (int i = t; i < NB1; i += THREADS) hist[i] = 0;
  __syncthreads();

  // Load row -> LDS (coalesced b128) and build pass-1 histogram from registers.
#pragma unroll
  for (int i = 0; i < HW / 4 / THREADS; ++i) {   // 16 iters
    const uint4 v = src[i * THREADS + t];
    data4[i * THREADS + t] = v;
    atomicAdd(&hist[(v.x & 0x7fffffffu) >> 20], 1u);
    atomicAdd(&hist[(v.y & 0x7fffffffu) >> 20], 1u);
    atomicAdd(&hist[(v.z & 0x7fffffffu) >> 20], 1u);
    atomicAdd(&hist[(v.w & 0x7fffffffu) >> 20], 1u);
  }
  __syncthreads();

  // Pass 1 select: bits [30:20]
  if (t < 64) wave_find(hist, NB1, K_SEL, &bc[0], &bc[1]);
  __syncthreads();
  const unsigned T1 = bc[0];
  unsigned kRem = bc[1];

  // Pass 2: among elements whose top digit == T1, histogram bits [19:10]
  for (int i = t; i < NB2; i += THREADS) hist[i] = 0;
  __syncthreads();
  for (int i = 0; i < HW / THREADS; ++i) {       // 64 iters, 4B/lane stride-1 -> conflict-free
    const unsigned a = data[i * THREADS + t] & 0x7fffffffu;
    if ((a >> 20) == T1) atomicAdd(&hist[(a >> 10) & (NB2 - 1)], 1u);
  }
  __syncthreads();
  if (t < 64) wave_find(hist, NB2, kRem, &bc[0], &bc[1]);
  __syncthreads();
  const unsigned pref2 = (T1 << 10) | bc[0];
  kRem = bc[1];

  // Pass 3: among elements matching pref2 (bits [30:10]), histogram bits [9:0]
  for (int i = t; i < NB2; i += THREADS) hist[i] = 0;
  __syncthreads();
  for (int i = 0; i < HW / THREADS; ++i) {
    const unsigned a = data[i * THREADS + t] & 0x7fffffffu;
    if ((a >> 10) == pref2) atomicAdd(&hist[a & (NB2 - 1)], 1u);
  }
  __syncthreads();
  if (t < 64) wave_find(hist, NB2, kRem, &bc[0], &bc[1]);
  __syncthreads();
  const unsigned thr = (pref2 << 10) | bc[0];    // exact k-th largest |x| bit pattern

  // Apply threshold (>= keeps ties, same as reference) and write out.
#pragma unroll
  for (int i = 0; i < HW / 4 / THREADS; ++i) {
    uint4 v = data4[i * THREADS + t];
    v.x = ((v.x & 0x7fffffffu) >= thr) ? v.x : 0u;
    v.y = ((v.y & 0x7fffffffu) >= thr) ? v.y : 0u;
    v.z = ((v.z & 0x7fffffffu) >= thr) ? v.z : 0u;
    v.w = ((v.w & 0x7fffffffu) >= thr) ? v.w : 0u;
    dst[i * THREADS + t] = v;
  }
}

extern "C" void kernel_launch(void* const* d_in, const int* in_sizes, int n_in,
                              void* d_out, int out_size, void* d_ws, size_t ws_size,
                              hipStream_t stream) {
  (void)n_in; (void)d_ws; (void)ws_size; (void)out_size;
  const float* x = (const float*)d_in[0];
  float* out = (float*)d_out;
  const int rows = in_sizes[0] / HW;                       // 32*128 = 4096
  const size_t shmem = (size_t)(HW + NB1 + 2) * sizeof(unsigned);  // 73,736 B
  sparsify_topk_kernel<<<dim3(rows), dim3(THREADS), shmem, stream>>>(x, out);
}

// Round 2
// 130.167 us; speedup vs baseline: 1.5946x; 1.5946x over previous
//
#include <hip/hip_runtime.h>

#define THREADS 256
#define HW 16384        // H*W per (b,c) row
#define K_SEL 8192      // k = 0.5 * H * W
#define NB1 2048        // pass-1 bins: abs bits [30:20]
#define NB2 1024        // pass-2/3 bins: 10 bits each
#define VPT 16          // uint4 per thread (64 floats)

// Find the kRem-th largest bin position in hist[nbins] (bins ascending in value).
// Executed by wave 0 only (threads 0..63). Writes selected bin and residual rank.
__device__ __forceinline__ void wave_find(const unsigned* hist, int nbins, unsigned kRem,
                                          unsigned* bc_bin, unsigned* bc_k) {
  const int lane = (int)threadIdx.x;          // 0..63
  const int bpl = nbins >> 6;                 // bins per lane (contiguous chunk)
  const int base = lane * bpl;
  // Bank-rotated chunk sum: lane l reads its bins in rotated order -> conflict-free.
  unsigned s = 0;
  for (int j = 0; j < bpl; ++j) s += hist[base + ((j + lane) & (bpl - 1))];
  // Inclusive suffix sum across lanes: suf_l = sum_{u>=l} s_u  (higher lanes = larger values)
  unsigned suf = s;
#pragma unroll
  for (int off = 1; off < 64; off <<= 1) {
    unsigned v = __shfl_down(suf, off);
    if (lane + off < 64) suf += v;
  }
  // Unique lane where cumAbove < kRem <= cumAbove + s  (cumAbove = suf - s)
  const bool hit = ((suf - s) < kRem) && (kRem <= suf);
  const unsigned long long m = __ballot(hit);
  const int tl = (int)__builtin_ctzll(m);
  if (lane == tl) {
    unsigned cum = suf - s;
    int bin = base + bpl - 1;
    for (;; --bin) {
      const unsigned h = hist[bin];
      if (cum + h >= kRem) { bc_bin[0] = (unsigned)bin; bc_k[0] = kRem - cum; break; }
      cum += h;
    }
  }
}

extern "C" __global__ __launch_bounds__(THREADS, 4)
void sparsify_topk_kernel(const float* __restrict__ x, float* __restrict__ out) {
  __shared__ unsigned hist1[NB1];
  __shared__ unsigned hist2[NB2];
  __shared__ unsigned hist3[NB2];
  __shared__ unsigned bc[2];

  const int t = (int)threadIdx.x;
  const size_t rowOff = (size_t)blockIdx.x * (HW / 4);
  const uint4* src = (const uint4*)x + rowOff;
  uint4*       dst = (uint4*)out + rowOff;

  // Zero all three histogram buffers once (disjoint buffers -> no mid-kernel re-zero).
  for (int i = t; i < NB1; i += THREADS) hist1[i] = 0;
  for (int i = t; i < NB2; i += THREADS) { hist2[i] = 0; hist3[i] = 0; }
  __syncthreads();

  // Load row into REGISTERS (64 floats/thread) and build pass-1 histogram.
  uint4 v[VPT];
#pragma unroll
  for (int i = 0; i < VPT; ++i) {
    v[i] = src[i * THREADS + t];
    atomicAdd(&hist1[(v[i].x & 0x7fffffffu) >> 20], 1u);
    atomicAdd(&hist1[(v[i].y & 0x7fffffffu) >> 20], 1u);
    atomicAdd(&hist1[(v[i].z & 0x7fffffffu) >> 20], 1u);
    atomicAdd(&hist1[(v[i].w & 0x7fffffffu) >> 20], 1u);
  }
  __syncthreads();

  // Pass 1 select: bits [30:20]
  if (t < 64) wave_find(hist1, NB1, K_SEL, &bc[0], &bc[1]);
  __syncthreads();
  const unsigned T1 = bc[0];
  unsigned kRem = bc[1];

  // Pass 2: among elements whose top digit == T1, histogram bits [19:10]
#pragma unroll
  for (int i = 0; i < VPT; ++i) {
    unsigned a;
    a = v[i].x & 0x7fffffffu; if ((a >> 20) == T1) atomicAdd(&hist2[(a >> 10) & (NB2 - 1)], 1u);
    a = v[i].y & 0x7fffffffu; if ((a >> 20) == T1) atomicAdd(&hist2[(a >> 10) & (NB2 - 1)], 1u);
    a = v[i].z & 0x7fffffffu; if ((a >> 20) == T1) atomicAdd(&hist2[(a >> 10) & (NB2 - 1)], 1u);
    a = v[i].w & 0x7fffffffu; if ((a >> 20) == T1) atomicAdd(&hist2[(a >> 10) & (NB2 - 1)], 1u);
  }
  __syncthreads();
  if (t < 64) wave_find(hist2, NB2, kRem, &bc[0], &bc[1]);
  __syncthreads();
  const unsigned pref2 = (T1 << 10) | bc[0];
  kRem = bc[1];

  // Pass 3: among elements matching pref2 (bits [30:10]), histogram bits [9:0]
#pragma unroll
  for (int i = 0; i < VPT; ++i) {
    unsigned a;
    a = v[i].x & 0x7fffffffu; if ((a >> 10) == pref2) atomicAdd(&hist3[a & (NB2 - 1)], 1u);
    a = v[i].y & 0x7fffffffu; if ((a >> 10) == pref2) atomicAdd(&hist3[a & (NB2 - 1)], 1u);
    a = v[i].z & 0x7fffffffu; if ((a >> 10) == pref2) atomicAdd(&hist3[a & (NB2 - 1)], 1u);
    a = v[i].w & 0x7fffffffu; if ((a >> 10) == pref2) atomicAdd(&hist3[a & (NB2 - 1)], 1u);
  }
  __syncthreads();
  if (t < 64) wave_find(hist3, NB2, kRem, &bc[0], &bc[1]);
  __syncthreads();
  const unsigned thr = (pref2 << 10) | bc[0];    // exact k-th largest |x| bit pattern

  // Apply threshold (>= keeps ties, same as reference) and write out from registers.
#pragma unroll
  for (int i = 0; i < VPT; ++i) {
    uint4 w = v[i];
    w.x = ((w.x & 0x7fffffffu) >= thr) ? w.x : 0u;
    w.y = ((w.y & 0x7fffffffu) >= thr) ? w.y : 0u;
    w.z = ((w.z & 0x7fffffffu) >= thr) ? w.z : 0u;
    w.w = ((w.w & 0x7fffffffu) >= thr) ? w.w : 0u;
    dst[i * THREADS + t] = w;
  }
}

extern "C" void kernel_launch(void* const* d_in, const int* in_sizes, int n_in,
                              void* d_out, int out_size, void* d_ws, size_t ws_size,
                              hipStream_t stream) {
  (void)n_in; (void)d_ws; (void)ws_size; (void)out_size;
  const float* x = (const float*)d_in[0];
  float* out = (float*)d_out;
  const int rows = in_sizes[0] / HW;   // 32*128 = 4096
  sparsify_topk_kernel<<<dim3(rows), dim3(THREADS), 0, stream>>>(x, out);
}